// Round 3
// baseline (277.064 us; speedup 1.0000x reference)
//
#include <hip/hip_runtime.h>

static constexpr int NN = 100000;   // nodes
static constexpr int NE = 3200000;  // edges
static constexpr int DI = 128;
static constexpr int DH = 64;
static constexpr int DO = 32;

static constexpr int NBK  = 391;    // dst buckets (dst>>8), 391*256 >= NN
static constexpr int BCAP = 9216;   // per-bucket capacity (mean 8184, +11 sigma)
static constexpr int TILE = 4096;   // edges per block in bucket pass (29KB LDS -> 5 blk/CU)
static constexpr int NEB  = (NE + TILE - 1) / TILE;  // 782 bucket blocks
static constexpr int XW1_BASE = NEB + 1;             // 783: [0,NEB)=bucket, NEB=castw
static constexpr int XW1_BLOCKS = (NN + 63) / 64;    // 1563

typedef short short8 __attribute__((ext_vector_type(8)));  // MFMA A/B frag
typedef float f32x4  __attribute__((ext_vector_type(4)));  // MFMA C/D frag

__device__ __forceinline__ unsigned short f2bf(float f) {
    union { float f; unsigned u; } v; v.f = f;
    unsigned r = v.u + 0x7FFFu + ((v.u >> 16) & 1u);  // RNE
    return (unsigned short)(r >> 16);
}
__device__ __forceinline__ float bflo(unsigned u) {
    union { unsigned u; float f; } v; v.u = u << 16; return v.f;
}
__device__ __forceinline__ float bfhi(unsigned u) {
    union { unsigned u; float f; } v; v.u = u & 0xFFFF0000u; return v.f;
}

// ---------------- zero bucket cursors ----------------
__global__ void k_zero(int* __restrict__ p, int n) {
    int i = blockIdx.x * blockDim.x + threadIdx.x;
    if (i < n) p[i] = 0;
}

// ---------------- mega: bucket pass || xw1 GEMM (fused cast) || cast W2 -----
__global__ __launch_bounds__(256) void k_mega(
        const int* __restrict__ src, const int* __restrict__ dst,
        int* __restrict__ bcur, int* __restrict__ bstore,
        const float* __restrict__ x, const float* __restrict__ W1,
        const float* __restrict__ W2,
        unsigned short* __restrict__ w2bf, unsigned short* __restrict__ h1b) {
    __shared__ int hist[NBK];
    __shared__ int lcur[NBK];
    __shared__ int gpos[NBK];
    __shared__ int stage[TILE];
    __shared__ unsigned short bid[TILE];

    int tid = threadIdx.x;

    if (blockIdx.x < NEB) {
        // ---- role A: LDS-aggregated bucketing of edges by dst>>8 ----
        for (int i = tid; i < NBK; i += 256) hist[i] = 0;
        __syncthreads();

        int base = blockIdx.x * TILE;
        int rem = NE - base;                 // multiple of 16 (NE % 16 == 0)
        int p[16]; unsigned short bb[16];
#pragma unroll
        for (int k4 = 0; k4 < 4; ++k4) {     // lane-major int4 edge loads
            int off = tid * 16 + k4 * 4;
            if (off < rem) {                 // off%4==0, rem%16==0 -> chunk fully valid
                int4 s4 = *(const int4*)(src + base + off);
                int4 d4 = *(const int4*)(dst + base + off);
                int k = 4 * k4;
                bb[k + 0] = (unsigned short)((unsigned)d4.x >> 8);
                p [k + 0] = ((d4.x & 255) << 24) | s4.x;
                atomicAdd(&hist[bb[k + 0]], 1);
                bb[k + 1] = (unsigned short)((unsigned)d4.y >> 8);
                p [k + 1] = ((d4.y & 255) << 24) | s4.y;
                atomicAdd(&hist[bb[k + 1]], 1);
                bb[k + 2] = (unsigned short)((unsigned)d4.z >> 8);
                p [k + 2] = ((d4.z & 255) << 24) | s4.z;
                atomicAdd(&hist[bb[k + 2]], 1);
                bb[k + 3] = (unsigned short)((unsigned)d4.w >> 8);
                p [k + 3] = ((d4.w & 255) << 24) | s4.w;
                atomicAdd(&hist[bb[k + 3]], 1);
            } else {
                int k = 4 * k4;
                bb[k + 0] = 0xFFFF; bb[k + 1] = 0xFFFF;
                bb[k + 2] = 0xFFFF; bb[k + 3] = 0xFFFF;
            }
        }
        __syncthreads();

        for (int i = tid; i < NBK; i += 256)
            gpos[i] = atomicAdd(&bcur[i], hist[i]);
        __syncthreads();

        if (tid < 64) {  // exclusive scan of hist (wave 0)
            int carry = 0;
            for (int c = 0; c < (NBK + 63) / 64; ++c) {
                int idx = c * 64 + tid;
                int v = (idx < NBK) ? hist[idx] : 0;
                int inc = v;
#pragma unroll
                for (int o = 1; o < 64; o <<= 1) {
                    int u = __shfl_up(inc, o, 64);
                    if (tid >= o) inc += u;
                }
                int tot = __shfl(inc, 63, 64);
                if (idx < NBK) { int ex = carry + inc - v; hist[idx] = ex; lcur[idx] = ex; }
                carry += tot;
            }
        }
        __syncthreads();

#pragma unroll
        for (int k = 0; k < 16; ++k) {
            if (bb[k] != 0xFFFF) {
                int lp = atomicAdd(&lcur[bb[k]], 1);
                stage[lp] = p[k];
                bid[lp] = bb[k];
            }
        }
        __syncthreads();

        int tcnt = min(TILE, rem);
        for (int i = tid; i < tcnt; i += 256) {
            int b = bid[i];
            int off = gpos[b] + (i - hist[b]);
            if (off < BCAP) bstore[b * BCAP + off] = stage[i];
        }
    } else if (blockIdx.x == NEB) {
        // ---- role B: cast W2 -> bf16 (W1 is converted in-reg by role C) ----
        for (int i = tid; i < DH * DO; i += 256) w2bf[i] = f2bf(W2[i]);
    } else {
        // ---- role C: h1b = bf16(x @ W1), fp32 inputs cast in-register ----
        int wave = tid >> 6, lane = tid & 63;
        int q = lane >> 4, m = lane & 15, o0 = wave * 16;
        int nb = (blockIdx.x - XW1_BASE) * 64;

        short8 bfr[4];  // B-frags for all 4 K-blocks (fp32 W1 -> bf16)
#pragma unroll
        for (int kb = 0; kb < 4; ++kb)
#pragma unroll
            for (int j = 0; j < 8; ++j)
                bfr[kb][j] = (short)f2bf(W1[(kb * 32 + q * 8 + j) * DH + o0 + m]);

#pragma unroll
        for (int mt = 0; mt < 4; ++mt) {
            int row = min(nb + mt * 16 + m, NN - 1);   // clamp overhang rows
            const float* xr = x + (size_t)row * DI;
            f32x4 acc = {0.f, 0.f, 0.f, 0.f};
#pragma unroll
            for (int kb = 0; kb < 4; ++kb) {
                f32x4 u0 = *(const f32x4*)(xr + kb * 32 + q * 8);
                f32x4 u1 = *(const f32x4*)(xr + kb * 32 + q * 8 + 4);
                short8 a;
                a[0] = (short)f2bf(u0.x); a[1] = (short)f2bf(u0.y);
                a[2] = (short)f2bf(u0.z); a[3] = (short)f2bf(u0.w);
                a[4] = (short)f2bf(u1.x); a[5] = (short)f2bf(u1.y);
                a[6] = (short)f2bf(u1.z); a[7] = (short)f2bf(u1.w);
                acc = __builtin_amdgcn_mfma_f32_16x16x32_bf16(a, bfr[kb], acc, 0, 0, 0);
            }
#pragma unroll
            for (int r = 0; r < 4; ++r) {
                int n = nb + mt * 16 + q * 4 + r;
                if (n < NN) h1b[(size_t)n * DH + o0 + m] = f2bf(acc[r]);  // unscaled
            }
        }
    }
}

// ---------------- per-bucket counting sort -> in-place CSR (512 thr) --------
// Tail: pre-scales this block's 256 h1b rows by dinv[n], so the layer-1
// gather needs NO per-edge dinv load (halves its VMEM request count).
__global__ __launch_bounds__(512) void k_bsort(
        const int* __restrict__ bcur, int* __restrict__ bstore,
        int* __restrict__ rpb, int* __restrict__ rpe, float* __restrict__ dinv,
        unsigned* __restrict__ h1) {
    __shared__ int buf[BCAP];
    __shared__ int sorted[BCAP];
    __shared__ int hist[256], scan[256], cur[256];
    __shared__ float sdinv[256];

    int b = blockIdx.x, tid = threadIdx.x;
    int cnt = min(bcur[b], BCAP);
    int base = b * BCAP;
    for (int i = tid; i < cnt; i += 512) buf[i] = bstore[base + i];
    if (tid < 256) hist[tid] = 0;
    __syncthreads();
    for (int i = tid; i < cnt; i += 512)
        atomicAdd(&hist[((unsigned)buf[i]) >> 24], 1);
    __syncthreads();

    if (tid < 64) {  // exclusive scan of 256 bins (wave 0)
        int carry = 0;
        for (int c = 0; c < 4; ++c) {
            int idx = c * 64 + tid;
            int v = hist[idx];
            int inc = v;
#pragma unroll
            for (int o = 1; o < 64; o <<= 1) {
                int u = __shfl_up(inc, o, 64);
                if (tid >= o) inc += u;
            }
            int tot = __shfl(inc, 63, 64);
            scan[idx] = carry + inc - v;
            cur[idx]  = carry + inc - v;
            carry += tot;
        }
    }
    __syncthreads();

    if (tid < 256) {
        int n = b * 256 + tid;
        if (n < NN) {
            int beg = base + scan[tid];
            rpb[n] = beg;
            rpe[n] = beg + hist[tid];
            float dv = rsqrtf(1.0f + (float)hist[tid]);
            dinv[n] = dv;
            sdinv[tid] = dv;
        }
    }

    for (int i = tid; i < cnt; i += 512) {
        unsigned pv = (unsigned)buf[i];
        int pos = atomicAdd(&cur[pv >> 24], 1);
        sorted[pos] = (int)(pv & 0xFFFFFF);
    }
    __syncthreads();
    for (int i = tid; i < cnt; i += 512) bstore[base + i] = sorted[i];

    // ---- pre-scale h1b rows of this block's nodes: h1[n] *= dinv[n] ----
    // (sdinv visible: written before the __syncthreads above the scatter)
    for (int i = tid; i < 2048; i += 512) {          // 256 rows x 8 uint4
        int r = i >> 3, n = b * 256 + r;
        if (n < NN) {
            float dv = sdinv[r];
            uint4* p = (uint4*)h1 + (size_t)b * 2048 + i;
            uint4 u = *p;
            u.x = (unsigned)f2bf(bflo(u.x) * dv) | ((unsigned)f2bf(bfhi(u.x) * dv) << 16);
            u.y = (unsigned)f2bf(bflo(u.y) * dv) | ((unsigned)f2bf(bfhi(u.y) * dv) << 16);
            u.z = (unsigned)f2bf(bflo(u.z) * dv) | ((unsigned)f2bf(bfhi(u.z) * dv) << 16);
            u.w = (unsigned)f2bf(bflo(u.w) * dv) | ((unsigned)f2bf(bfhi(u.w) * dv) << 16);
            *p = u;
        }
    }
}

// ---------------- gather layer 1 (uint2 loads, prescaled rows) --------------
// Wave = 1 node. lane = 16*q + f4. h rows are PRE-SCALED by dinv[src], so
// sum = sum_e h[s_e] + h[n]; t = relu(dinv[n]*sum + b1). No per-edge dinv
// load -> VMEM requests in the hot loop halve vs the 274us baseline.
__global__ __launch_bounds__(256) void k_gather64(
        const int* __restrict__ rpb, const int* __restrict__ rpe,
        const int* __restrict__ csr, const unsigned* __restrict__ h,
        const float* __restrict__ dinv, const float* __restrict__ b1,
        unsigned* __restrict__ tbf) {
    int wave = threadIdx.x >> 6, lane = threadIdx.x & 63;
    int q = lane >> 4, f4 = lane & 15;
    int n = blockIdx.x * 4 + wave;
    int beg = rpb[n], end = rpe[n];
    float dn = dinv[n];

    float s0 = 0.f, s1 = 0.f, s2 = 0.f, s3 = 0.f;
    if (q == 0) {                       // self-loop: prescaled row = dinv[n]*h1[n]
        uint2 u = *(const uint2*)(h + (size_t)n * 32 + 2 * f4);
        s0 = bflo(u.x); s1 = bfhi(u.x); s2 = bflo(u.y); s3 = bfhi(u.y);
    }
    for (int c = beg; c < end; c += 64) {
        int cnt = min(64, end - c);
        int sidx = (lane < cnt) ? csr[c + lane] : 0;
        int j = 0;
        for (; j + 16 <= cnt; j += 16) {   // 16 edges/iter, 4 loads/lane in flight
            int sa = __shfl(sidx, j + q, 64);
            int sb = __shfl(sidx, j + 4 + q, 64);
            int sc = __shfl(sidx, j + 8 + q, 64);
            int sd = __shfl(sidx, j + 12 + q, 64);
            uint2 ua = *(const uint2*)(h + (size_t)sa * 32 + 2 * f4);
            uint2 ub = *(const uint2*)(h + (size_t)sb * 32 + 2 * f4);
            uint2 uc = *(const uint2*)(h + (size_t)sc * 32 + 2 * f4);
            uint2 ud = *(const uint2*)(h + (size_t)sd * 32 + 2 * f4);
            s0 += bflo(ua.x); s1 += bfhi(ua.x); s2 += bflo(ua.y); s3 += bfhi(ua.y);
            s0 += bflo(ub.x); s1 += bfhi(ub.x); s2 += bflo(ub.y); s3 += bfhi(ub.y);
            s0 += bflo(uc.x); s1 += bfhi(uc.x); s2 += bflo(uc.y); s3 += bfhi(uc.y);
            s0 += bflo(ud.x); s1 += bfhi(ud.x); s2 += bflo(ud.y); s3 += bfhi(ud.y);
        }
        for (; j + 8 <= cnt; j += 8) {     // 8-edge step
            int sa = __shfl(sidx, j + q, 64);
            int sb = __shfl(sidx, j + 4 + q, 64);
            uint2 ua = *(const uint2*)(h + (size_t)sa * 32 + 2 * f4);
            uint2 ub = *(const uint2*)(h + (size_t)sb * 32 + 2 * f4);
            s0 += bflo(ua.x); s1 += bfhi(ua.x); s2 += bflo(ua.y); s3 += bfhi(ua.y);
            s0 += bflo(ub.x); s1 += bfhi(ub.x); s2 += bflo(ub.y); s3 += bfhi(ub.y);
        }
        for (; j < cnt; j += 4) {          // tail, predicated
            int slot = j + q;              // j<=60, q<=3 -> slot<=63, shfl safe
            int s = __shfl(sidx, slot, 64);
            if (slot < cnt) {
                uint2 u = *(const uint2*)(h + (size_t)s * 32 + 2 * f4);
                s0 += bflo(u.x); s1 += bfhi(u.x); s2 += bflo(u.y); s3 += bfhi(u.y);
            }
        }
    }
    s0 += __shfl_xor(s0, 32, 64); s1 += __shfl_xor(s1, 32, 64);
    s2 += __shfl_xor(s2, 32, 64); s3 += __shfl_xor(s3, 32, 64);
    s0 += __shfl_xor(s0, 16, 64); s1 += __shfl_xor(s1, 16, 64);
    s2 += __shfl_xor(s2, 16, 64); s3 += __shfl_xor(s3, 16, 64);
    if (q == 0) {
        float t0 = fmaxf(fmaf(s0, dn, b1[4 * f4 + 0]), 0.f);
        float t1 = fmaxf(fmaf(s1, dn, b1[4 * f4 + 1]), 0.f);
        float t2 = fmaxf(fmaf(s2, dn, b1[4 * f4 + 2]), 0.f);
        float t3 = fmaxf(fmaf(s3, dn, b1[4 * f4 + 3]), 0.f);
        uint2 o;
        o.x = (unsigned)f2bf(t0) | ((unsigned)f2bf(t1) << 16);
        o.y = (unsigned)f2bf(t2) | ((unsigned)f2bf(t3) << 16);
        *(uint2*)(tbf + (size_t)n * 32 + 2 * f4) = o;
    }
}

// ---------------- layer 2 GEMM (MFMA): h2b = bf16((t @ W2) * dinv) ----------
__global__ __launch_bounds__(256) void k_l2_mfma(
        const unsigned short* __restrict__ tbf, const unsigned short* __restrict__ w2bf,
        const float* __restrict__ dinv, unsigned short* __restrict__ h2b) {
    int wave = threadIdx.x >> 6, lane = threadIdx.x & 63;
    int q = lane >> 4, m = lane & 15;
    int o0 = (wave & 1) * 16, mt = wave >> 1;
    int nb = blockIdx.x * 32;

    short8 bf[2];
#pragma unroll
    for (int kb = 0; kb < 2; ++kb)
#pragma unroll
        for (int j = 0; j < 8; ++j)
            bf[kb][j] = (short)w2bf[(kb * 32 + q * 8 + j) * DO + o0 + m];

    int row = nb + mt * 16 + m;
    f32x4 acc = {0.f, 0.f, 0.f, 0.f};
#pragma unroll
    for (int kb = 0; kb < 2; ++kb) {
        short8 a = *(const short8*)(tbf + (size_t)row * DH + kb * 32 + q * 8);
        acc = __builtin_amdgcn_mfma_f32_16x16x32_bf16(a, bf[kb], acc, 0, 0, 0);
    }
#pragma unroll
    for (int r = 0; r < 4; ++r) {
        int n = nb + mt * 16 + q * 4 + r;
        if (n < NN) h2b[(size_t)n * DO + o0 + m] = f2bf(acc[r] * dinv[n]);
    }
}

// ---------------- gather layer 2 (uint2 loads, 8-slot MLP) ------------------
__global__ __launch_bounds__(256) void k_gather32(
        const int* __restrict__ rpb, const int* __restrict__ rpe,
        const int* __restrict__ csr, const unsigned* __restrict__ h,
        const float* __restrict__ dinv, const float* __restrict__ b2,
        float* __restrict__ out) {
    int wave = threadIdx.x >> 6, lane = threadIdx.x & 63;
    int q = lane >> 3, f4 = lane & 7;
    int n = blockIdx.x * 4 + wave;
    int beg = rpb[n], end = rpe[n];

    float s0 = 0.f, s1 = 0.f, s2 = 0.f, s3 = 0.f;
    if (q == 0) {                       // self-loop counted once
        uint2 u = *(const uint2*)(h + (size_t)n * 16 + 2 * f4);
        s0 = bflo(u.x); s1 = bfhi(u.x); s2 = bflo(u.y); s3 = bfhi(u.y);
    }
    for (int c = beg; c < end; c += 64) {
        int cnt = min(64, end - c);
        int sidx = (lane < cnt) ? csr[c + lane] : 0;
        int j = 0;
        for (; j + 16 <= cnt; j += 16) {  // 16 edges/iter, 2 loads/lane
            int sa = __shfl(sidx, j + q, 64);
            int sb = __shfl(sidx, j + 8 + q, 64);
            uint2 ua = *(const uint2*)(h + (size_t)sa * 16 + 2 * f4);
            uint2 ub = *(const uint2*)(h + (size_t)sb * 16 + 2 * f4);
            s0 += bflo(ua.x); s1 += bfhi(ua.x); s2 += bflo(ua.y); s3 += bfhi(ua.y);
            s0 += bflo(ub.x); s1 += bfhi(ub.x); s2 += bflo(ub.y); s3 += bfhi(ub.y);
        }
        for (; j < cnt; j += 8) {         // tail, predicated
            int slot = j + q;             // j<=56, q<=7 -> slot<=63, shfl safe
            int s = __shfl(sidx, slot, 64);
            if (slot < cnt) {
                uint2 u = *(const uint2*)(h + (size_t)s * 16 + 2 * f4);
                s0 += bflo(u.x); s1 += bfhi(u.x); s2 += bflo(u.y); s3 += bfhi(u.y);
            }
        }
    }
    s0 += __shfl_xor(s0, 32, 64); s1 += __shfl_xor(s1, 32, 64);
    s2 += __shfl_xor(s2, 32, 64); s3 += __shfl_xor(s3, 32, 64);
    s0 += __shfl_xor(s0, 16, 64); s1 += __shfl_xor(s1, 16, 64);
    s2 += __shfl_xor(s2, 16, 64); s3 += __shfl_xor(s3, 16, 64);
    s0 += __shfl_xor(s0, 8, 64);  s1 += __shfl_xor(s1, 8, 64);
    s2 += __shfl_xor(s2, 8, 64);  s3 += __shfl_xor(s3, 8, 64);
    if (q == 0) {
        float dn = dinv[n];
        size_t o = (size_t)n * 32 + 4 * f4;
        out[o + 0] = fmaf(s0, dn, b2[4 * f4 + 0]);
        out[o + 1] = fmaf(s1, dn, b2[4 * f4 + 1]);
        out[o + 2] = fmaf(s2, dn, b2[4 * f4 + 2]);
        out[o + 3] = fmaf(s3, dn, b2[4 * f4 + 3]);
    }
}

extern "C" void kernel_launch(void* const* d_in, const int* in_sizes, int n_in,
                              void* d_out, int out_size, void* d_ws, size_t ws_size,
                              hipStream_t stream) {
    const float* x  = (const float*)d_in[0];
    const float* W1 = (const float*)d_in[1];
    const float* b1 = (const float*)d_in[2];
    const float* W2 = (const float*)d_in[3];
    const float* b2 = (const float*)d_in[4];
    const int* ei  = (const int*)d_in[5];
    const int* src = ei;        // edge_index[0]
    const int* dst = ei + NE;   // edge_index[1]
    float* out = (float*)d_out;

    // workspace layout (4 B words), total ~10.3M words = 41.3 MB:
    float* ws    = (float*)d_ws;
    int*   rpb   = (int*)ws;                          // 100,352
    int*   rpe   = (int*)(ws + 100352);               // 100,352
    float* dinv  = ws + 200704;                       // 100,352
    int*   bcur  = (int*)(ws + 301056);               // 512
    int*   bstor = (int*)(ws + 301568);               // 3,603,456
    unsigned short* w2bf = (unsigned short*)(ws + 3905024);   // 2,048 bf16 (1,024 w)
    unsigned short* tbf  = (unsigned short*)(ws + 3906048);   // 100,000x64 bf16 (3.2M w)
    unsigned short* h1b  = (unsigned short*)(ws + 7106048);   // 100,000x64 bf16 (3.2M w)
    unsigned short* h2b  = h1b;   // reuse (h1b dead after gather64); 100,000x32 bf16

    k_zero     <<<2, 256, 0, stream>>>(bcur, 512);
    k_mega     <<<XW1_BASE + XW1_BLOCKS, 256, 0, stream>>>(
                    src, dst, bcur, bstor, x, W1, W2, w2bf, h1b);
    k_bsort    <<<NBK, 512, 0, stream>>>(bcur, bstor, rpb, rpe, dinv,
                                         (unsigned*)h1b);

    k_gather64 <<<NN / 4, 256, 0, stream>>>(rpb, rpe, bstor, (const unsigned*)h1b,
                                            dinv, b1, (unsigned*)tbf);
    k_l2_mfma  <<<NN / 32, 256, 0, stream>>>(tbf, w2bf, dinv, h2b);
    k_gather32 <<<NN / 4, 256, 0, stream>>>(rpb, rpe, bstor, (const unsigned*)h2b,
                                            dinv, b2, out);
}

// Round 4
// 275.192 us; speedup vs baseline: 1.0068x; 1.0068x over previous
//
#include <hip/hip_runtime.h>

static constexpr int NN = 100000;   // nodes
static constexpr int NE = 3200000;  // edges
static constexpr int DI = 128;
static constexpr int DH = 64;
static constexpr int DO = 32;

static constexpr int NBK  = 391;    // dst buckets (dst>>8), 391*256 >= NN
static constexpr int BCAP = 9216;   // per-bucket capacity (mean 8184, +11 sigma)
static constexpr int TILE = 4096;   // edges per block in bucket pass (29KB LDS)
static constexpr int NEB  = (NE + TILE - 1) / TILE;  // 782 bucket blocks
static constexpr int NEBP = 784;    // padded row length of the count matrix
static constexpr int XW1_BASE = NEB + 1;             // 783: [0,NEB)=bucket, NEB=castw
static constexpr int XW1_BLOCKS = (NN + 63) / 64;    // 1563

typedef short short8 __attribute__((ext_vector_type(8)));  // MFMA A/B frag
typedef float f32x4  __attribute__((ext_vector_type(4)));  // MFMA C/D frag

__device__ __forceinline__ unsigned short f2bf(float f) {
    union { float f; unsigned u; } v; v.f = f;
    unsigned r = v.u + 0x7FFFu + ((v.u >> 16) & 1u);  // RNE
    return (unsigned short)(r >> 16);
}
__device__ __forceinline__ float bflo(unsigned u) {
    union { unsigned u; float f; } v; v.u = u << 16; return v.f;
}
__device__ __forceinline__ float bfhi(unsigned u) {
    union { unsigned u; float f; } v; v.u = u & 0xFFFF0000u; return v.f;
}

// ---------------- count pass: cnt[bucket][block] = per-chunk histogram ------
// Plain global writes -- NO contended global atomics anywhere.
__global__ __launch_bounds__(256) void k_count(
        const int* __restrict__ dst, int* __restrict__ cnt) {
    __shared__ int hist[NBK];
    int tid = threadIdx.x;
    for (int i = tid; i < NBK; i += 256) hist[i] = 0;
    __syncthreads();

    int base = blockIdx.x * TILE;
    int rem = NE - base;                 // rem % 16 == 0
#pragma unroll
    for (int k4 = 0; k4 < 4; ++k4) {
        int off = tid * 16 + k4 * 4;
        if (off < rem) {                 // off%4==0, rem%16==0 -> chunk fully valid
            int4 d4 = *(const int4*)(dst + base + off);
            atomicAdd(&hist[(unsigned)d4.x >> 8], 1);
            atomicAdd(&hist[(unsigned)d4.y >> 8], 1);
            atomicAdd(&hist[(unsigned)d4.z >> 8], 1);
            atomicAdd(&hist[(unsigned)d4.w >> 8], 1);
        }
    }
    __syncthreads();
    for (int i = tid; i < NBK; i += 256)
        cnt[i * NEBP + blockIdx.x] = hist[i];
}

// ---------------- scan pass: per bucket, exclusive scan over blocks ---------
// cnt[b][blk] -> exclusive prefix (in place); bcur[b] = bucket total.
__global__ __launch_bounds__(64) void k_scan(
        int* __restrict__ cnt, int* __restrict__ bcur) {
    int b = blockIdx.x, tid = threadIdx.x;
    int* row = cnt + b * NEBP;
    int carry = 0;
    for (int c = 0; c < (NEB + 63) / 64; ++c) {
        int idx = c * 64 + tid;
        int v = (idx < NEB) ? row[idx] : 0;
        int inc = v;
#pragma unroll
        for (int o = 1; o < 64; o <<= 1) {
            int u = __shfl_up(inc, o, 64);
            if (tid >= o) inc += u;
        }
        int tot = __shfl(inc, 63, 64);
        if (idx < NEB) row[idx] = carry + inc - v;
        carry += tot;
    }
    if (tid == 0) bcur[b] = carry;
}

// ---------------- mega: bucket scatter || xw1 GEMM (fused cast) || cast W2 --
__global__ __launch_bounds__(256) void k_mega(
        const int* __restrict__ src, const int* __restrict__ dst,
        const int* __restrict__ gposM, int* __restrict__ bstore,
        const float* __restrict__ x, const float* __restrict__ W1,
        const float* __restrict__ W2,
        unsigned short* __restrict__ w2bf, unsigned short* __restrict__ h1b) {
    __shared__ int hist[NBK];
    __shared__ int lcur[NBK];
    __shared__ int gpos[NBK];
    __shared__ int stage[TILE];
    __shared__ unsigned short bid[TILE];

    int tid = threadIdx.x;

    if (blockIdx.x < NEB) {
        // ---- role A: LDS-aggregated bucketing of edges by dst>>8 ----
        for (int i = tid; i < NBK; i += 256) hist[i] = 0;
        __syncthreads();

        int base = blockIdx.x * TILE;
        int rem = NE - base;                 // multiple of 16 (NE % 16 == 0)
        int p[16]; unsigned short bb[16];
#pragma unroll
        for (int k4 = 0; k4 < 4; ++k4) {     // lane-major int4 edge loads
            int off = tid * 16 + k4 * 4;
            if (off < rem) {                 // off%4==0, rem%16==0 -> chunk fully valid
                int4 s4 = *(const int4*)(src + base + off);
                int4 d4 = *(const int4*)(dst + base + off);
                int k = 4 * k4;
                bb[k + 0] = (unsigned short)((unsigned)d4.x >> 8);
                p [k + 0] = ((d4.x & 255) << 24) | s4.x;
                atomicAdd(&hist[bb[k + 0]], 1);
                bb[k + 1] = (unsigned short)((unsigned)d4.y >> 8);
                p [k + 1] = ((d4.y & 255) << 24) | s4.y;
                atomicAdd(&hist[bb[k + 1]], 1);
                bb[k + 2] = (unsigned short)((unsigned)d4.z >> 8);
                p [k + 2] = ((d4.z & 255) << 24) | s4.z;
                atomicAdd(&hist[bb[k + 2]], 1);
                bb[k + 3] = (unsigned short)((unsigned)d4.w >> 8);
                p [k + 3] = ((d4.w & 255) << 24) | s4.w;
                atomicAdd(&hist[bb[k + 3]], 1);
            } else {
                int k = 4 * k4;
                bb[k + 0] = 0xFFFF; bb[k + 1] = 0xFFFF;
                bb[k + 2] = 0xFFFF; bb[k + 3] = 0xFFFF;
            }
        }
        __syncthreads();

        // precomputed scatter bases: plain loads, no atomics, no stall
        for (int i = tid; i < NBK; i += 256)
            gpos[i] = gposM[i * NEBP + blockIdx.x];
        __syncthreads();

        if (tid < 64) {  // exclusive scan of hist (wave 0)
            int carry = 0;
            for (int c = 0; c < (NBK + 63) / 64; ++c) {
                int idx = c * 64 + tid;
                int v = (idx < NBK) ? hist[idx] : 0;
                int inc = v;
#pragma unroll
                for (int o = 1; o < 64; o <<= 1) {
                    int u = __shfl_up(inc, o, 64);
                    if (tid >= o) inc += u;
                }
                int tot = __shfl(inc, 63, 64);
                if (idx < NBK) { int ex = carry + inc - v; hist[idx] = ex; lcur[idx] = ex; }
                carry += tot;
            }
        }
        __syncthreads();

#pragma unroll
        for (int k = 0; k < 16; ++k) {
            if (bb[k] != 0xFFFF) {
                int lp = atomicAdd(&lcur[bb[k]], 1);
                stage[lp] = p[k];
                bid[lp] = bb[k];
            }
        }
        __syncthreads();

        int tcnt = min(TILE, rem);
        for (int i = tid; i < tcnt; i += 256) {
            int b = bid[i];
            int off = gpos[b] + (i - hist[b]);
            if (off < BCAP) bstore[b * BCAP + off] = stage[i];
        }
    } else if (blockIdx.x == NEB) {
        // ---- role B: cast W2 -> bf16 (W1 is converted in-reg by role C) ----
        for (int i = tid; i < DH * DO; i += 256) w2bf[i] = f2bf(W2[i]);
    } else {
        // ---- role C: h1b = bf16(x @ W1), fp32 inputs cast in-register ----
        int wave = tid >> 6, lane = tid & 63;
        int q = lane >> 4, m = lane & 15, o0 = wave * 16;
        int nb = (blockIdx.x - XW1_BASE) * 64;

        short8 bfr[4];  // B-frags for all 4 K-blocks (fp32 W1 -> bf16)
#pragma unroll
        for (int kb = 0; kb < 4; ++kb)
#pragma unroll
            for (int j = 0; j < 8; ++j)
                bfr[kb][j] = (short)f2bf(W1[(kb * 32 + q * 8 + j) * DH + o0 + m]);

#pragma unroll
        for (int mt = 0; mt < 4; ++mt) {
            int row = min(nb + mt * 16 + m, NN - 1);   // clamp overhang rows
            const float* xr = x + (size_t)row * DI;
            f32x4 acc = {0.f, 0.f, 0.f, 0.f};
#pragma unroll
            for (int kb = 0; kb < 4; ++kb) {
                f32x4 u0 = *(const f32x4*)(xr + kb * 32 + q * 8);
                f32x4 u1 = *(const f32x4*)(xr + kb * 32 + q * 8 + 4);
                short8 a;
                a[0] = (short)f2bf(u0.x); a[1] = (short)f2bf(u0.y);
                a[2] = (short)f2bf(u0.z); a[3] = (short)f2bf(u0.w);
                a[4] = (short)f2bf(u1.x); a[5] = (short)f2bf(u1.y);
                a[6] = (short)f2bf(u1.z); a[7] = (short)f2bf(u1.w);
                acc = __builtin_amdgcn_mfma_f32_16x16x32_bf16(a, bfr[kb], acc, 0, 0, 0);
            }
#pragma unroll
            for (int r = 0; r < 4; ++r) {
                int n = nb + mt * 16 + q * 4 + r;
                if (n < NN) h1b[(size_t)n * DH + o0 + m] = f2bf(acc[r]);  // unscaled
            }
        }
    }
}

// ---------------- per-bucket counting sort -> in-place CSR (512 thr) --------
// Tail: pre-scales this block's 256 h1b rows by dinv[n], so the layer-1
// gather needs NO per-edge dinv load (halves its VMEM request count).
__global__ __launch_bounds__(512) void k_bsort(
        const int* __restrict__ bcur, int* __restrict__ bstore,
        int* __restrict__ rpb, int* __restrict__ rpe, float* __restrict__ dinv,
        unsigned* __restrict__ h1) {
    __shared__ int buf[BCAP];
    __shared__ int sorted[BCAP];
    __shared__ int hist[256], scan[256], cur[256];
    __shared__ float sdinv[256];

    int b = blockIdx.x, tid = threadIdx.x;
    int cnt = min(bcur[b], BCAP);
    int base = b * BCAP;
    for (int i = tid; i < cnt; i += 512) buf[i] = bstore[base + i];
    if (tid < 256) hist[tid] = 0;
    __syncthreads();
    for (int i = tid; i < cnt; i += 512)
        atomicAdd(&hist[((unsigned)buf[i]) >> 24], 1);
    __syncthreads();

    if (tid < 64) {  // exclusive scan of 256 bins (wave 0)
        int carry = 0;
        for (int c = 0; c < 4; ++c) {
            int idx = c * 64 + tid;
            int v = hist[idx];
            int inc = v;
#pragma unroll
            for (int o = 1; o < 64; o <<= 1) {
                int u = __shfl_up(inc, o, 64);
                if (tid >= o) inc += u;
            }
            int tot = __shfl(inc, 63, 64);
            scan[idx] = carry + inc - v;
            cur[idx]  = carry + inc - v;
            carry += tot;
        }
    }
    __syncthreads();

    if (tid < 256) {
        int n = b * 256 + tid;
        if (n < NN) {
            int beg = base + scan[tid];
            rpb[n] = beg;
            rpe[n] = beg + hist[tid];
            float dv = rsqrtf(1.0f + (float)hist[tid]);
            dinv[n] = dv;
            sdinv[tid] = dv;
        }
    }

    for (int i = tid; i < cnt; i += 512) {
        unsigned pv = (unsigned)buf[i];
        int pos = atomicAdd(&cur[pv >> 24], 1);
        sorted[pos] = (int)(pv & 0xFFFFFF);
    }
    __syncthreads();
    for (int i = tid; i < cnt; i += 512) bstore[base + i] = sorted[i];

    // ---- pre-scale h1b rows of this block's nodes: h1[n] *= dinv[n] ----
    // (sdinv visible: written before the __syncthreads above the scatter)
    for (int i = tid; i < 2048; i += 512) {          // 256 rows x 8 uint4
        int r = i >> 3, n = b * 256 + r;
        if (n < NN) {
            float dv = sdinv[r];
            uint4* p = (uint4*)h1 + (size_t)b * 2048 + i;
            uint4 u = *p;
            u.x = (unsigned)f2bf(bflo(u.x) * dv) | ((unsigned)f2bf(bfhi(u.x) * dv) << 16);
            u.y = (unsigned)f2bf(bflo(u.y) * dv) | ((unsigned)f2bf(bfhi(u.y) * dv) << 16);
            u.z = (unsigned)f2bf(bflo(u.z) * dv) | ((unsigned)f2bf(bfhi(u.z) * dv) << 16);
            u.w = (unsigned)f2bf(bflo(u.w) * dv) | ((unsigned)f2bf(bfhi(u.w) * dv) << 16);
            *p = u;
        }
    }
}

// ---------------- gather layer 1 (uint2 loads, prescaled rows) --------------
// Wave = 1 node. lane = 16*q + f4. h rows are PRE-SCALED by dinv[src], so
// sum = sum_e h[s_e] + h[n]; t = relu(dinv[n]*sum + b1). No per-edge dinv
// load -> VMEM requests in the hot loop halve vs the 274us baseline.
__global__ __launch_bounds__(256) void k_gather64(
        const int* __restrict__ rpb, const int* __restrict__ rpe,
        const int* __restrict__ csr, const unsigned* __restrict__ h,
        const float* __restrict__ dinv, const float* __restrict__ b1,
        unsigned* __restrict__ tbf) {
    int wave = threadIdx.x >> 6, lane = threadIdx.x & 63;
    int q = lane >> 4, f4 = lane & 15;
    int n = blockIdx.x * 4 + wave;
    int beg = rpb[n], end = rpe[n];
    float dn = dinv[n];

    float s0 = 0.f, s1 = 0.f, s2 = 0.f, s3 = 0.f;
    if (q == 0) {                       // self-loop: prescaled row = dinv[n]*h1[n]
        uint2 u = *(const uint2*)(h + (size_t)n * 32 + 2 * f4);
        s0 = bflo(u.x); s1 = bfhi(u.x); s2 = bflo(u.y); s3 = bfhi(u.y);
    }
    for (int c = beg; c < end; c += 64) {
        int cnt = min(64, end - c);
        int sidx = (lane < cnt) ? csr[c + lane] : 0;
        int j = 0;
        for (; j + 16 <= cnt; j += 16) {   // 16 edges/iter, 4 loads/lane in flight
            int sa = __shfl(sidx, j + q, 64);
            int sb = __shfl(sidx, j + 4 + q, 64);
            int sc = __shfl(sidx, j + 8 + q, 64);
            int sd = __shfl(sidx, j + 12 + q, 64);
            uint2 ua = *(const uint2*)(h + (size_t)sa * 32 + 2 * f4);
            uint2 ub = *(const uint2*)(h + (size_t)sb * 32 + 2 * f4);
            uint2 uc = *(const uint2*)(h + (size_t)sc * 32 + 2 * f4);
            uint2 ud = *(const uint2*)(h + (size_t)sd * 32 + 2 * f4);
            s0 += bflo(ua.x); s1 += bfhi(ua.x); s2 += bflo(ua.y); s3 += bfhi(ua.y);
            s0 += bflo(ub.x); s1 += bfhi(ub.x); s2 += bflo(ub.y); s3 += bfhi(ub.y);
            s0 += bflo(uc.x); s1 += bfhi(uc.x); s2 += bflo(uc.y); s3 += bfhi(uc.y);
            s0 += bflo(ud.x); s1 += bfhi(ud.x); s2 += bflo(ud.y); s3 += bfhi(ud.y);
        }
        for (; j + 8 <= cnt; j += 8) {     // 8-edge step
            int sa = __shfl(sidx, j + q, 64);
            int sb = __shfl(sidx, j + 4 + q, 64);
            uint2 ua = *(const uint2*)(h + (size_t)sa * 32 + 2 * f4);
            uint2 ub = *(const uint2*)(h + (size_t)sb * 32 + 2 * f4);
            s0 += bflo(ua.x); s1 += bfhi(ua.x); s2 += bflo(ua.y); s3 += bfhi(ua.y);
            s0 += bflo(ub.x); s1 += bfhi(ub.x); s2 += bflo(ub.y); s3 += bfhi(ub.y);
        }
        for (; j < cnt; j += 4) {          // tail, predicated
            int slot = j + q;              // j<=60, q<=3 -> slot<=63, shfl safe
            int s = __shfl(sidx, slot, 64);
            if (slot < cnt) {
                uint2 u = *(const uint2*)(h + (size_t)s * 32 + 2 * f4);
                s0 += bflo(u.x); s1 += bfhi(u.x); s2 += bflo(u.y); s3 += bfhi(u.y);
            }
        }
    }
    s0 += __shfl_xor(s0, 32, 64); s1 += __shfl_xor(s1, 32, 64);
    s2 += __shfl_xor(s2, 32, 64); s3 += __shfl_xor(s3, 32, 64);
    s0 += __shfl_xor(s0, 16, 64); s1 += __shfl_xor(s1, 16, 64);
    s2 += __shfl_xor(s2, 16, 64); s3 += __shfl_xor(s3, 16, 64);
    if (q == 0) {
        float t0 = fmaxf(fmaf(s0, dn, b1[4 * f4 + 0]), 0.f);
        float t1 = fmaxf(fmaf(s1, dn, b1[4 * f4 + 1]), 0.f);
        float t2 = fmaxf(fmaf(s2, dn, b1[4 * f4 + 2]), 0.f);
        float t3 = fmaxf(fmaf(s3, dn, b1[4 * f4 + 3]), 0.f);
        uint2 o;
        o.x = (unsigned)f2bf(t0) | ((unsigned)f2bf(t1) << 16);
        o.y = (unsigned)f2bf(t2) | ((unsigned)f2bf(t3) << 16);
        *(uint2*)(tbf + (size_t)n * 32 + 2 * f4) = o;
    }
}

// ---------------- layer 2 GEMM (MFMA): h2b = bf16((t @ W2) * dinv) ----------
__global__ __launch_bounds__(256) void k_l2_mfma(
        const unsigned short* __restrict__ tbf, const unsigned short* __restrict__ w2bf,
        const float* __restrict__ dinv, unsigned short* __restrict__ h2b) {
    int wave = threadIdx.x >> 6, lane = threadIdx.x & 63;
    int q = lane >> 4, m = lane & 15;
    int o0 = (wave & 1) * 16, mt = wave >> 1;
    int nb = blockIdx.x * 32;

    short8 bf[2];
#pragma unroll
    for (int kb = 0; kb < 2; ++kb)
#pragma unroll
        for (int j = 0; j < 8; ++j)
            bf[kb][j] = (short)w2bf[(kb * 32 + q * 8 + j) * DO + o0 + m];

    int row = nb + mt * 16 + m;
    f32x4 acc = {0.f, 0.f, 0.f, 0.f};
#pragma unroll
    for (int kb = 0; kb < 2; ++kb) {
        short8 a = *(const short8*)(tbf + (size_t)row * DH + kb * 32 + q * 8);
        acc = __builtin_amdgcn_mfma_f32_16x16x32_bf16(a, bf[kb], acc, 0, 0, 0);
    }
#pragma unroll
    for (int r = 0; r < 4; ++r) {
        int n = nb + mt * 16 + q * 4 + r;
        if (n < NN) h2b[(size_t)n * DO + o0 + m] = f2bf(acc[r] * dinv[n]);
    }
}

// ---------------- gather layer 2 (uint2 loads, 8-slot MLP) ------------------
__global__ __launch_bounds__(256) void k_gather32(
        const int* __restrict__ rpb, const int* __restrict__ rpe,
        const int* __restrict__ csr, const unsigned* __restrict__ h,
        const float* __restrict__ dinv, const float* __restrict__ b2,
        float* __restrict__ out) {
    int wave = threadIdx.x >> 6, lane = threadIdx.x & 63;
    int q = lane >> 3, f4 = lane & 7;
    int n = blockIdx.x * 4 + wave;
    int beg = rpb[n], end = rpe[n];

    float s0 = 0.f, s1 = 0.f, s2 = 0.f, s3 = 0.f;
    if (q == 0) {                       // self-loop counted once
        uint2 u = *(const uint2*)(h + (size_t)n * 16 + 2 * f4);
        s0 = bflo(u.x); s1 = bfhi(u.x); s2 = bflo(u.y); s3 = bfhi(u.y);
    }
    for (int c = beg; c < end; c += 64) {
        int cnt = min(64, end - c);
        int sidx = (lane < cnt) ? csr[c + lane] : 0;
        int j = 0;
        for (; j + 16 <= cnt; j += 16) {  // 16 edges/iter, 2 loads/lane
            int sa = __shfl(sidx, j + q, 64);
            int sb = __shfl(sidx, j + 8 + q, 64);
            uint2 ua = *(const uint2*)(h + (size_t)sa * 16 + 2 * f4);
            uint2 ub = *(const uint2*)(h + (size_t)sb * 16 + 2 * f4);
            s0 += bflo(ua.x); s1 += bfhi(ua.x); s2 += bflo(ua.y); s3 += bfhi(ua.y);
            s0 += bflo(ub.x); s1 += bfhi(ub.x); s2 += bflo(ub.y); s3 += bfhi(ub.y);
        }
        for (; j < cnt; j += 8) {         // tail, predicated
            int slot = j + q;             // j<=56, q<=7 -> slot<=63, shfl safe
            int s = __shfl(sidx, slot, 64);
            if (slot < cnt) {
                uint2 u = *(const uint2*)(h + (size_t)s * 16 + 2 * f4);
                s0 += bflo(u.x); s1 += bfhi(u.x); s2 += bflo(u.y); s3 += bfhi(u.y);
            }
        }
    }
    s0 += __shfl_xor(s0, 32, 64); s1 += __shfl_xor(s1, 32, 64);
    s2 += __shfl_xor(s2, 32, 64); s3 += __shfl_xor(s3, 32, 64);
    s0 += __shfl_xor(s0, 16, 64); s1 += __shfl_xor(s1, 16, 64);
    s2 += __shfl_xor(s2, 16, 64); s3 += __shfl_xor(s3, 16, 64);
    s0 += __shfl_xor(s0, 8, 64);  s1 += __shfl_xor(s1, 8, 64);
    s2 += __shfl_xor(s2, 8, 64);  s3 += __shfl_xor(s3, 8, 64);
    if (q == 0) {
        float dn = dinv[n];
        size_t o = (size_t)n * 32 + 4 * f4;
        out[o + 0] = fmaf(s0, dn, b2[4 * f4 + 0]);
        out[o + 1] = fmaf(s1, dn, b2[4 * f4 + 1]);
        out[o + 2] = fmaf(s2, dn, b2[4 * f4 + 2]);
        out[o + 3] = fmaf(s3, dn, b2[4 * f4 + 3]);
    }
}

extern "C" void kernel_launch(void* const* d_in, const int* in_sizes, int n_in,
                              void* d_out, int out_size, void* d_ws, size_t ws_size,
                              hipStream_t stream) {
    const float* x  = (const float*)d_in[0];
    const float* W1 = (const float*)d_in[1];
    const float* b1 = (const float*)d_in[2];
    const float* W2 = (const float*)d_in[3];
    const float* b2 = (const float*)d_in[4];
    const int* ei  = (const int*)d_in[5];
    const int* src = ei;        // edge_index[0]
    const int* dst = ei + NE;   // edge_index[1]
    float* out = (float*)d_out;

    // workspace layout (4 B words), total ~10.3M words = 41.3 MB:
    float* ws    = (float*)d_ws;
    int*   rpb   = (int*)ws;                          // 100,352
    int*   rpe   = (int*)(ws + 100352);               // 100,352
    float* dinv  = ws + 200704;                       // 100,352
    int*   bcur  = (int*)(ws + 301056);               // 512 (only 391 used)
    int*   bstor = (int*)(ws + 301568);               // 3,603,456
    unsigned short* w2bf = (unsigned short*)(ws + 3905024);   // 2,048 bf16 (1,024 w)
    unsigned short* tbf  = (unsigned short*)(ws + 3906048);   // 100,000x64 bf16 (3.2M w)
    unsigned short* h1b  = (unsigned short*)(ws + 7106048);   // 100,000x64 bf16 (3.2M w)
    unsigned short* h2b  = h1b;   // reuse (h1b dead after gather64); 100,000x32 bf16
    // count/offset matrix [NBK][NEBP] = 306,544 words, aliased into the tbf
    // region (tbf is first written by k_gather64, AFTER k_mega consumed cnt).
    int*   cntM  = (int*)tbf;

    k_count    <<<NEB, 256, 0, stream>>>(dst, cntM);
    k_scan     <<<NBK, 64, 0, stream>>>(cntM, bcur);
    k_mega     <<<XW1_BASE + XW1_BLOCKS, 256, 0, stream>>>(
                    src, dst, cntM, bstor, x, W1, W2, w2bf, h1b);
    k_bsort    <<<NBK, 512, 0, stream>>>(bcur, bstor, rpb, rpe, dinv,
                                         (unsigned*)h1b);

    k_gather64 <<<NN / 4, 256, 0, stream>>>(rpb, rpe, bstor, (const unsigned*)h1b,
                                            dinv, b1, (unsigned*)tbf);
    k_l2_mfma  <<<NN / 32, 256, 0, stream>>>(tbf, w2bf, dinv, h2b);
    k_gather32 <<<NN / 4, 256, 0, stream>>>(rpb, rpe, bstor, (const unsigned*)h2b,
                                            dinv, b2, out);
}